// Round 1
// baseline (259.951 us; speedup 1.0000x reference)
//
#include <hip/hip_runtime.h>

// AvgSeq: out[b,s,d] = (sum_{t<=s} x[b,t,d]) / (s+1)
// x: [16, 8192, 256] float32
#define BB 16
#define SS 8192
#define DD 256
#define NC 64          // chunks along S
#define CL (SS / NC)   // 128 steps per chunk

// K1: per-chunk column sums -> ws[b][c][d]
__global__ __launch_bounds__(256) void avgseq_chunksum(const float* __restrict__ x,
                                                       float* __restrict__ ws) {
    const int blk = blockIdx.x;        // b*NC + c
    const int b = blk / NC;
    const int c = blk % NC;
    const int d = threadIdx.x;

    const float* p = x + ((size_t)b * SS + (size_t)c * CL) * DD + d;
    float acc = 0.0f;
#pragma unroll 8
    for (int s = 0; s < CL; ++s) {
        acc += p[(size_t)s * DD];
    }
    ws[((size_t)b * NC + c) * DD + d] = acc;
}

// K2: prefix from preceding chunk sums, then sequential scan + divide
__global__ __launch_bounds__(256) void avgseq_scan(const float* __restrict__ x,
                                                   const float* __restrict__ ws,
                                                   float* __restrict__ out) {
    const int blk = blockIdx.x;        // b*NC + c
    const int b = blk / NC;
    const int c = blk % NC;
    const int d = threadIdx.x;

    // prefix = sum of chunk sums for chunks < c (coalesced reads, small)
    const float* w = ws + (size_t)b * NC * DD + d;
    float prefix = 0.0f;
    for (int cc = 0; cc < c; ++cc) {
        prefix += w[(size_t)cc * DD];
    }

    const size_t base = ((size_t)b * SS + (size_t)c * CL) * DD + d;
    const float* p = x + base;
    float* o = out + base;
    const int s0 = c * CL;

    float acc = prefix;
#pragma unroll 4
    for (int s = 0; s < CL; ++s) {
        acc += p[(size_t)s * DD];
        o[(size_t)s * DD] = acc / (float)(s0 + s + 1);
    }
}

extern "C" void kernel_launch(void* const* d_in, const int* in_sizes, int n_in,
                              void* d_out, int out_size, void* d_ws, size_t ws_size,
                              hipStream_t stream) {
    const float* x = (const float*)d_in[0];
    float* out = (float*)d_out;
    float* ws = (float*)d_ws;   // BB*NC*DD floats = 1 MiB

    const int nblocks = BB * NC;   // 1024
    avgseq_chunksum<<<nblocks, DD, 0, stream>>>(x, ws);
    avgseq_scan<<<nblocks, DD, 0, stream>>>(x, ws, out);
}

// Round 2
// 259.237 us; speedup vs baseline: 1.0028x; 1.0028x over previous
//
#include <hip/hip_runtime.h>

// AvgSeq: out[b,s,d] = (sum_{t<=s} x[b,t,d]) / (s+1)
// x: [16, 8192, 256] float32
//
// Two-pass chunked scan, float4-vectorized:
//   K1: chunk sums -> ws   (one wave per (b,chunk), lane = float4 column)
//   K2: prefix over preceding chunk sums, then serial scan of own chunk.
#define BB 16
#define SS 8192
#define DD 256
#define D4 (DD / 4)     // 64 float4 columns; one wave covers all of D
#define NC 128          // chunks along S
#define CL (SS / NC)    // 64 steps per chunk

__global__ __launch_bounds__(64) void avgseq_chunksum(const float4* __restrict__ x,
                                                      float4* __restrict__ ws) {
    const int blk = blockIdx.x;          // b*NC + c
    const int b = blk >> 7;              // / NC
    const int c = blk & (NC - 1);
    const int t = threadIdx.x;           // float4 column

    const float4* p = x + ((size_t)b * SS + (size_t)c * CL) * D4 + t;
    float4 acc = make_float4(0.f, 0.f, 0.f, 0.f);
#pragma unroll 8
    for (int s = 0; s < CL; ++s) {
        float4 v = p[(size_t)s * D4];
        acc.x += v.x; acc.y += v.y; acc.z += v.z; acc.w += v.w;
    }
    ws[((size_t)b * NC + c) * D4 + t] = acc;
}

__global__ __launch_bounds__(64) void avgseq_scan(const float4* __restrict__ x,
                                                  const float4* __restrict__ ws,
                                                  float4* __restrict__ out) {
    const int blk = blockIdx.x;          // b*NC + c
    const int b = blk >> 7;
    const int c = blk & (NC - 1);
    const int t = threadIdx.x;

    // prefix = sum of chunk sums for chunks < c (small, L2-resident)
    const float4* w = ws + (size_t)b * NC * D4 + t;
    float4 pre = make_float4(0.f, 0.f, 0.f, 0.f);
#pragma unroll 4
    for (int cc = 0; cc < c; ++cc) {
        float4 v = w[(size_t)cc * D4];
        pre.x += v.x; pre.y += v.y; pre.z += v.z; pre.w += v.w;
    }

    const size_t base = ((size_t)b * SS + (size_t)c * CL) * D4 + t;
    const float4* p = x + base;
    float4* o = out + base;
    const int s0 = c * CL;

    float4 acc = pre;
#pragma unroll 8
    for (int s = 0; s < CL; ++s) {
        float4 v = p[(size_t)s * D4];
        acc.x += v.x; acc.y += v.y; acc.z += v.z; acc.w += v.w;
        const float r = __builtin_amdgcn_rcpf((float)(s0 + s + 1));
        float4 ov = make_float4(acc.x * r, acc.y * r, acc.z * r, acc.w * r);
        o[(size_t)s * D4] = ov;
    }
}

extern "C" void kernel_launch(void* const* d_in, const int* in_sizes, int n_in,
                              void* d_out, int out_size, void* d_ws, size_t ws_size,
                              hipStream_t stream) {
    const float4* x = (const float4*)d_in[0];
    float4* out = (float4*)d_out;
    float4* ws = (float4*)d_ws;          // BB*NC*D4 float4 = 2 MiB

    const int nblocks = BB * NC;         // 2048 single-wave blocks = 8 waves/CU
    avgseq_chunksum<<<nblocks, 64, 0, stream>>>(x, ws);
    avgseq_scan<<<nblocks, 64, 0, stream>>>(x, ws, out);
}